// Round 6
// baseline (218.785 us; speedup 1.0000x reference)
//
#include <hip/hip_runtime.h>

#define NUM_REGIONS 32
#define NBINS 33                        // ws layout keeps 33 (bin 0 unused)
#define BATCH 4
#define DHW (160*192*192)               // 5,898,240 per volume, divisible by 4
#define NVEC_PER_BATCH (DHW/4)          // 1,474,560 float4 vectors per batch
#define BLOCKS_PER_BATCH 256
#define NBLOCKS (BATCH*BLOCKS_PER_BATCH)                 // 1024 = 4 per CU
#define VEC_PER_BLOCK (NVEC_PER_BATCH/BLOCKS_PER_BATCH)  // 5760
#define FULL_ITERS (VEC_PER_BLOCK/256)                   // 22 (5632 vectors)
#define TAIL_START (FULL_ITERS*256)                      // 5632; tail = 128 thr
#define RED_STRIDE 257                  // bank = (bin + col) % 32
#define EPS 1e-8f

// ---------------------------------------------------------------------------
// Kernel 1 (R6): REGISTER histogram on the VALU — no LDS ops in the hot loop.
// R5 proved the DS atomic unit is the floor (~2.1 cy/lane, per-CU serial);
// the VALU is 4x/CU. 32 per-lane f32 accumulators (bins 1..32; bin 0 of the
// reference is discarded, seg==0 simply matches nothing). Unrolled
// cmp+cndmask+add per bin, inline constants only. Packed accumulate
// V = xs + 256*cnt per lane-bin (<=92 elems/lane-bin -> xs < 96 < 256, exact).
// Block-end: LDS transpose reduce (2-way bank aliasing = free), then one
// global atomic pair per bin.
// ws layout: ws[0..132) = xs sums (float), ws[132..264) = counts (float).
// ---------------------------------------------------------------------------
__global__ __launch_bounds__(256, 4) void region_sums_kernel(
    const float* __restrict__ x,
    const int*   __restrict__ seg,
    float*       __restrict__ ws)
{
    __shared__ float red[32 * RED_STRIDE];   // 32,896 B
    __shared__ float part_xs [8][32];        //  1,024 B
    __shared__ float part_cnt[8][32];        //  1,024 B

    float acc[32];
    #pragma unroll
    for (int b = 0; b < 32; ++b) acc[b] = 0.0f;

    const int tid   = threadIdx.x;
    const int batch = blockIdx.x >> 8;       // 256 blocks per batch
    const int local = blockIdx.x & 255;
    const int vbase = batch * NVEC_PER_BATCH + local * VEC_PER_BLOCK;

    const float4* __restrict__ xv4 = (const float4*)x;
    const int4*   __restrict__ sv4 = (const int4*)seg;

    // 2-deep rolling prefetch, named registers
    float4 xA = xv4[vbase + tid];       int4 sA = sv4[vbase + tid];
    float4 xB = xv4[vbase + tid + 256]; int4 sB = sv4[vbase + tid + 256];

    #pragma unroll 1
    for (int k = 0; k < FULL_ITERS; ++k) {
        const int kn = (k + 2 < FULL_ITERS) ? (k + 2) : (FULL_ITERS - 1);
        float4 xN = xv4[vbase + kn * 256 + tid];
        int4   sN = sv4[vbase + kn * 256 + tid];

        float p0 = __fdividef(1.0f, 1.0f + __expf(-xA.x)) + 256.0f;
        float p1 = __fdividef(1.0f, 1.0f + __expf(-xA.y)) + 256.0f;
        float p2 = __fdividef(1.0f, 1.0f + __expf(-xA.z)) + 256.0f;
        float p3 = __fdividef(1.0f, 1.0f + __expf(-xA.w)) + 256.0f;

        // 32-bin scatter on the VALU: 3 VOPs per (element, bin), all inline
        // consts, compile-time acc indices (full unroll), 32 independent
        // dependency chains -> high ILP.
        #pragma unroll
        for (int b = 0; b < 32; ++b) {
            acc[b] += (sA.x == b + 1) ? p0 : 0.0f;
            acc[b] += (sA.y == b + 1) ? p1 : 0.0f;
            acc[b] += (sA.z == b + 1) ? p2 : 0.0f;
            acc[b] += (sA.w == b + 1) ? p3 : 0.0f;
        }

        xA = xB; sA = sB; xB = xN; sB = sN;
    }

    // tail: vectors 5632..5759 (first 128 threads)
    if (tid < VEC_PER_BLOCK - TAIL_START) {
        float4 xT = xv4[vbase + TAIL_START + tid];
        int4   sT = sv4[vbase + TAIL_START + tid];
        float p0 = __fdividef(1.0f, 1.0f + __expf(-xT.x)) + 256.0f;
        float p1 = __fdividef(1.0f, 1.0f + __expf(-xT.y)) + 256.0f;
        float p2 = __fdividef(1.0f, 1.0f + __expf(-xT.z)) + 256.0f;
        float p3 = __fdividef(1.0f, 1.0f + __expf(-xT.w)) + 256.0f;
        #pragma unroll
        for (int b = 0; b < 32; ++b) {
            acc[b] += (sT.x == b + 1) ? p0 : 0.0f;
            acc[b] += (sT.y == b + 1) ? p1 : 0.0f;
            acc[b] += (sT.z == b + 1) ? p2 : 0.0f;
            acc[b] += (sT.w == b + 1) ? p3 : 0.0f;
        }
    }

    // spill per-lane accumulators to LDS: red[bin][tid], banks 2-way (free)
    #pragma unroll
    for (int b = 0; b < 32; ++b) red[b * RED_STRIDE + tid] = acc[b];
    __syncthreads();

    // Phase A: thread (g, bin) sums 32 of the 256 columns of its bin,
    // unpacking cnt = trunc(V/256), xs = V - 256*cnt (exact: xs < 96 < 256).
    {
        const int bin = tid & 31;            // 0..31 <-> regions 1..32
        const int g   = tid >> 5;            // 0..7
        float xs = 0.0f, cnt = 0.0f;
        #pragma unroll
        for (int j = 0; j < 32; ++j) {
            float V = red[bin * RED_STRIDE + g * 32 + j];
            float c = truncf(V * (1.0f / 256.0f));
            cnt += c;
            xs  += V - 256.0f * c;
        }
        part_xs [g][bin] = xs;
        part_cnt[g][bin] = cnt;
    }
    __syncthreads();

    if (tid < 32) {
        float xs = 0.0f, cnt = 0.0f;
        #pragma unroll
        for (int g = 0; g < 8; ++g) {
            xs  += part_xs [g][tid];
            cnt += part_cnt[g][tid];
        }
        atomicAdd(&ws[batch * NBINS + tid + 1], xs);
        atomicAdd(&ws[BATCH * NBINS + batch * NBINS + tid + 1], cnt);
    }
}

// ---------------------------------------------------------------------------
// Kernel 2: dice + mean epilogue. One wave; lane r handles region r (1..32).
// ---------------------------------------------------------------------------
__global__ void region_dice_final_kernel(
    const float* __restrict__ ws,
    float*       __restrict__ out)
{
    const int lane = threadIdx.x;   // 0..63
    float loss_sum = 0.0f;

    for (int b = 0; b < BATCH; ++b) {
        bool  valid = false;
        float dice  = 0.0f;
        if (lane >= 1 && lane <= NUM_REGIONS) {
            float xs  = ws[b * NBINS + lane];
            float cnt = ws[BATCH * NBINS + b * NBINS + lane];
            valid = (cnt > 0.0f);
            if (valid) dice = 2.0f * xs / (xs + cnt + EPS);
        }
        unsigned long long m = __ballot(valid);
        int n_valid = __popcll(m);

        float s = dice;
        #pragma unroll
        for (int off = 32; off >= 1; off >>= 1) s += __shfl_down(s, off);

        float mean_dice = s / (float)((n_valid > 1) ? n_valid : 1);
        float loss_b    = (n_valid > 0) ? (1.0f - mean_dice) : 1.0f;
        loss_sum += loss_b;
    }

    if (lane == 0) out[0] = loss_sum * (1.0f / BATCH);
}

extern "C" void kernel_launch(void* const* d_in, const int* in_sizes, int n_in,
                              void* d_out, int out_size, void* d_ws, size_t ws_size,
                              hipStream_t stream)
{
    const float* x   = (const float*)d_in[0];
    const int*   seg = (const int*)d_in[1];
    float*       ws  = (float*)d_ws;

    // d_ws is poisoned with 0xAA before every timed launch — zero the bins.
    hipMemsetAsync(d_ws, 0, 2 * BATCH * NBINS * sizeof(float), stream);

    region_sums_kernel<<<NBLOCKS, 256, 0, stream>>>(x, seg, ws);
    region_dice_final_kernel<<<1, 64, 0, stream>>>(ws, (float*)d_out);
}